// Round 8
// baseline (187.285 us; speedup 1.0000x reference)
//
#include <hip/hip_runtime.h>
#include <hip/hip_bf16.h>
#include <stdint.h>

typedef __attribute__((ext_vector_type(8))) short s16x8;
typedef __attribute__((ext_vector_type(4))) float f32x4;

#define T_   2048
#define NH   16
#define HD   64
#define DIN  1024
#define SCALE_LOG2 0.18033688011112042f  // (1/8)*log2(e)

#define MFMA32(a, b, c) __builtin_amdgcn_mfma_f32_16x16x32_bf16(a, b, c, 0, 0, 0)

// RTNE fp32 -> bf16
__device__ __forceinline__ unsigned short f2bf(float f) {
  union { float f; uint32_t u; } c; c.f = f;
  uint32_t u = c.u;
  return (unsigned short)((u + 0x7FFFu + ((u >> 16) & 1u)) >> 16);
}

__device__ __forceinline__ uint32_t pk_bf16(float a, float b) {
  __hip_bfloat162 h = __float22bfloat162_rn(make_float2(a, b));
  return *reinterpret_cast<uint32_t*>(&h);
}

// async global->LDS, 16B per lane; dest = wave-uniform base + lane*16
#define GLL(gp, lp) __builtin_amdgcn_global_load_lds( \
    (__attribute__((address_space(1))) void*)(gp),    \
    (__attribute__((address_space(3))) void*)(lp), 16, 0, 0)

// ---------------- kernel 1: fp32 -> bf16 conversion ----------------
__global__ __launch_bounds__(256) void cvt_kernel(
    const float* __restrict__ x,  const float* __restrict__ wq,
    const float* __restrict__ wk, const float* __restrict__ wv,
    unsigned short* __restrict__ xb, unsigned short* __restrict__ wb) {
  int i = (blockIdx.x * 256 + threadIdx.x) * 4;
  float4 v;
  unsigned short* dp;
  if (i < 4194304) {
    v = *(const float4*)(x + i);
    dp = xb + i;
  } else {
    int j = i - 4194304;
    int seg = j >> 20, r = j & 1048575;
    const float* w = (seg == 0) ? wq : (seg == 1) ? wk : wv;
    v = *(const float4*)(w + r);
    dp = wb + j;
  }
  ushort4 o;
  o.x = f2bf(v.x); o.y = f2bf(v.y); o.z = f2bf(v.z); o.w = f2bf(v.w);
  *(ushort4*)dp = o;
}

// ---------------- kernel 2: QKV projection GEMM ----------------
// Proven r0 version (BK=64, 64x128 tiles, 24KB LDS, 6 blocks/CU). BK=128
// (r7) was neutral -> reverted to minimize confounds this round.
__global__ __launch_bounds__(256) void qkv_gemm(
    const unsigned short* __restrict__ A, const unsigned short* __restrict__ Bm,
    unsigned short* __restrict__ qkv) {
  __shared__ __attribute__((aligned(16))) unsigned short Alds[64 * 64];
  __shared__ __attribute__((aligned(16))) unsigned short Blds[128 * 64];
  const int tid = threadIdx.x;
  const int lane = tid & 63, wave = tid >> 6;
  const int wm = wave >> 1, wn = wave & 1;  // 2x2 waves over 64x128
  const int m0 = blockIdx.y * 64, n0 = blockIdx.x * 128;

  f32x4 acc[2][4] = {};

  const int srA = wave * 16 + (lane >> 3);  // A staging row (2 issues x 8)
  const int srB = wave * 32 + (lane >> 3);  // B staging row (4 issues x 8)
  const int scol = (((lane & 7) ^ ((lane >> 3) & 7))) * 8;
  const unsigned short* ag = A  + (size_t)(m0 + srA) * DIN + scol;
  const unsigned short* bg = Bm + (size_t)(n0 + srB) * DIN + scol;
  unsigned short* al = &Alds[wave * 16 * 64];
  unsigned short* bl = &Blds[wave * 32 * 64];

  const int l16 = lane & 15, quad = lane >> 4;
  const int sw = l16 & 7;

  for (int k0 = 0; k0 < DIN; k0 += 64) {
    __syncthreads();
#pragma unroll
    for (int i = 0; i < 2; i++)
      GLL(ag + (size_t)i * 8 * DIN + k0, al + i * 512);
#pragma unroll
    for (int i = 0; i < 4; i++)
      GLL(bg + (size_t)i * 8 * DIN + k0, bl + i * 512);
    __syncthreads();
#pragma unroll
    for (int ks = 0; ks < 2; ks++) {
      const int cl = ((ks * 4 + quad) ^ sw) * 8;
      s16x8 af[2], bf[4];
#pragma unroll
      for (int mt = 0; mt < 2; mt++)
        af[mt] = *(const s16x8*)&Alds[(wm * 32 + mt * 16 + l16) * 64 + cl];
#pragma unroll
      for (int nt = 0; nt < 4; nt++)
        bf[nt] = *(const s16x8*)&Blds[(wn * 64 + nt * 16 + l16) * 64 + cl];
#pragma unroll
      for (int mt = 0; mt < 2; mt++)
#pragma unroll
        for (int nt = 0; nt < 4; nt++)
          acc[mt][nt] = MFMA32(af[mt], bf[nt], acc[mt][nt]);
    }
  }

#pragma unroll
  for (int mt = 0; mt < 2; mt++) {
    int mbase = m0 + wm * 32 + mt * 16 + (quad << 2);
    int b = mbase >> 11, t = mbase & 2047;
#pragma unroll
    for (int nt = 0; nt < 4; nt++) {
      int n = n0 + wn * 64 + nt * 16 + l16;
      int sel = n >> 10, h = (n >> 6) & 15, d = n & 63;
      int bh = b * NH + h;
      if (sel == 2) {
        ushort4 pk;
        pk.x = f2bf(acc[mt][nt][0]); pk.y = f2bf(acc[mt][nt][1]);
        pk.z = f2bf(acc[mt][nt][2]); pk.w = f2bf(acc[mt][nt][3]);
        *(ushort4*)&qkv[8388608 + (size_t)(bh * HD + d) * T_ + t] = pk;
      } else {
        float qs = (sel == 0) ? SCALE_LOG2 : 1.f;  // fold softmax scale into Q
#pragma unroll
        for (int r = 0; r < 4; r++)
          qkv[(size_t)sel * 4194304 + (size_t)(bh * T_ + t + r) * HD + d] =
              f2bf(acc[mt][nt][r] * qs);
      }
    }
  }
}

// -------- kernel 3: causal flash attention (v8: 32q/wave, LDS-BW fix) -----
// Model from r0-r7 data: CU tile throughput saturates at ~1030cy/unit with
// ~770cy of that being LDS pipe (88 b128-eq per 64x64 unit at 16q/wave --
// K/V frags re-read by every wave). v8: 32 q/wave x 4 waves = 128-q blocks;
// per 64-k tile the SAME K/V reads serve 2 tile-units -> ~56 b128-eq/unit
// (-36%). Inner 32q/wave body lifted verbatim from v2 (HW-passed); staging
// = v5's proven reg-prefetch. LDS 32KB (K 8K + V 8K + P[128][64] 16K) ->
// 5 blocks/CU, 20 waves. Balance: split-k chunks of <=8 k-tiles, 40 LPT-
// ordered jobs/bh, grid 32x40=1280 (=5/CU, worst-CU ~1.12x mean). Mask:
// tile kt masked iff kt>=2*qt with lim = qib - (kt-2qt)*64 (negative ->
// all-zero rows). qt<4 direct; qt>=4 f32 (O,l) partials (36 slots/bh),
// combine sums <=4 chunks.
__global__ __launch_bounds__(256) void attn_kernel(
    const unsigned short* __restrict__ qkv, float* __restrict__ out,
    float* __restrict__ op, float* __restrict__ lp) {
  __shared__ __attribute__((aligned(16))) unsigned short Klds[64 * 64];
  __shared__ __attribute__((aligned(16))) unsigned short Vt[64 * 64];
  __shared__ __attribute__((aligned(16))) unsigned short Plds[128 * 64];

  const int tid = threadIdx.x;
  const int lane = tid & 63, wave = tid >> 6;
  const int l16 = lane & 15, quad = lane >> 4;
  const int swl = l16 & 7;
  const int bh = blockIdx.x;

  // LPT job table: y<28 = len-8 chunks, then len 6,6,6,6,4,4,4,4,2,2,2,2.
  static const unsigned char QTt[40] = {
      3, 4, 5, 6, 7, 7, 8, 8, 9, 9, 10, 10, 11, 11, 11, 12, 12, 12,
      13, 13, 13, 14, 14, 14, 15, 15, 15, 15,
      2, 6, 10, 14, 1, 5, 9, 13, 0, 4, 8, 12};
  static const unsigned char CCt[40] = {
      0, 0, 0, 0, 0, 1, 0, 1, 0, 1, 0, 1, 0, 1, 2, 0, 1, 2,
      0, 1, 2, 0, 1, 2, 0, 1, 2, 3,
      0, 1, 2, 3, 0, 1, 2, 3, 0, 1, 2, 3};
  const int qt = QTt[blockIdx.y], c = CCt[blockIdx.y];
  const int kt0 = c * 8;
  const int kt1 = min(kt0 + 7, 2 * qt + 1);
  const bool split = (qt >= 4);

  const size_t bh_off = (size_t)bh * (T_ * HD);
  const unsigned short* Q  = qkv + bh_off;            // [t][d], pre-scaled
  const unsigned short* Kb = qkv + 4194304 + bh_off;  // [t][d]
  const unsigned short* Vb = qkv + 8388608 + bh_off;  // [d][t]
  const int q0 = qt * 128;

  // Q fragments: 32 q-rows per wave (B-operand, n = q) -- v2 layout
  s16x8 qf[2][2];
#pragma unroll
  for (int nt = 0; nt < 2; nt++) {
    const unsigned short* qp =
        Q + (size_t)(q0 + wave * 32 + nt * 16 + l16) * HD + quad * 8;
    qf[nt][0] = *(const s16x8*)(qp);
    qf[nt][1] = *(const s16x8*)(qp + 32);
  }

  // K/V staging: reg prefetch, XOR-swizzled LDS write (proven v5)
  const int sr = tid >> 3;                 // staging row 0..31
  const int sc = (tid & 7) * 8;            // linear global chunk
  const int swc = (((tid & 7) ^ (sr & 7))) * 8;  // swizzled LDS chunk

  s16x8 kr0 = *(const s16x8*)&Kb[(size_t)(kt0 * 64 + sr) * HD + sc];
  s16x8 kr1 = *(const s16x8*)&Kb[(size_t)(kt0 * 64 + sr + 32) * HD + sc];
  s16x8 vr0 = *(const s16x8*)&Vb[(size_t)sr * T_ + kt0 * 64 + sc];
  s16x8 vr1 = *(const s16x8*)&Vb[(size_t)(sr + 32) * T_ + kt0 * 64 + sc];

  const s16x8 onesf = {0x3F80, 0x3F80, 0x3F80, 0x3F80,
                       0x3F80, 0x3F80, 0x3F80, 0x3F80};  // bf16 1.0 x8
  f32x4 o[2][4] = {};
  f32x4 lacc[2] = {};

  for (int kt = kt0; kt <= kt1; kt++) {
    __syncthreads();
    *(s16x8*)&Klds[sr * 64 + swc] = kr0;
    *(s16x8*)&Klds[(sr + 32) * 64 + swc] = kr1;
    *(s16x8*)&Vt[sr * 64 + swc] = vr0;
    *(s16x8*)&Vt[(sr + 32) * 64 + swc] = vr1;
    if (kt < kt1) {  // prefetch next k-tile
      const unsigned short* kp = Kb + (size_t)(kt + 1) * 64 * HD;
      const unsigned short* vp = Vb + (kt + 1) * 64;
      kr0 = *(const s16x8*)&kp[(size_t)sr * HD + sc];
      kr1 = *(const s16x8*)&kp[(size_t)(sr + 32) * HD + sc];
      vr0 = *(const s16x8*)&vp[(size_t)sr * T_ + sc];
      vr1 = *(const s16x8*)&vp[(size_t)(sr + 32) * T_ + sc];
    }
    __syncthreads();

    // S^T = K @ Q^T : m = key (64), n = q (32 per wave)  [v2 body]
    f32x4 s[4][2] = {};
#pragma unroll
    for (int kk = 0; kk < 2; kk++) {
      const int cl = ((kk * 4 + quad) ^ swl) * 8;
#pragma unroll
      for (int mt = 0; mt < 4; mt++) {
        s16x8 kf = *(const s16x8*)&Klds[(mt * 16 + l16) * 64 + cl];
#pragma unroll
        for (int nt = 0; nt < 2; nt++)
          s[mt][nt] = MFMA32(kf, qf[nt][kk], s[mt][nt]);
      }
    }

    // P = exp2(S) -> LDS bf16 (v2 layout; rows wave*32+nt*16+l16)
    if (kt < 2 * qt) {  // fully visible tile
#pragma unroll
      for (int nt = 0; nt < 2; nt++) {
        uint32_t* prow = (uint32_t*)&Plds[(wave * 32 + nt * 16 + l16) * 64];
#pragma unroll
        for (int mt = 0; mt < 4; mt++) {
          float p0 = exp2f(s[mt][nt][0]);
          float p1 = exp2f(s[mt][nt][1]);
          float p2 = exp2f(s[mt][nt][2]);
          float p3 = exp2f(s[mt][nt][3]);
          *(uint2*)&prow[(((2 * mt + (quad >> 1)) ^ swl) << 2) +
                         (quad & 1) * 2] =
              make_uint2(pk_bf16(p0, p1), pk_bf16(p2, p3));
        }
      }
    } else {  // diagonal-region tile: causal mask with row shift
      const int dsh = (kt - 2 * qt) * 64;
#pragma unroll
      for (int nt = 0; nt < 2; nt++) {
        const int lim = wave * 32 + nt * 16 + l16 - dsh;
        uint32_t* prow = (uint32_t*)&Plds[(wave * 32 + nt * 16 + l16) * 64];
#pragma unroll
        for (int mt = 0; mt < 4; mt++) {
          const int kb = mt * 16 + quad * 4;
          float p0 = (kb + 0 <= lim) ? exp2f(s[mt][nt][0]) : 0.f;
          float p1 = (kb + 1 <= lim) ? exp2f(s[mt][nt][1]) : 0.f;
          float p2 = (kb + 2 <= lim) ? exp2f(s[mt][nt][2]) : 0.f;
          float p3 = (kb + 3 <= lim) ? exp2f(s[mt][nt][3]) : 0.f;
          *(uint2*)&prow[(((2 * mt + (quad >> 1)) ^ swl) << 2) +
                         (quad & 1) * 2] =
              make_uint2(pk_bf16(p0, p1), pk_bf16(p2, p3));
        }
      }
    }

    // O += P @ V ; l += P @ 1  (same-wave P rows)
#pragma unroll
    for (int kk = 0; kk < 2; kk++) {
      const int cl = ((kk * 4 + quad) ^ swl) * 8;
      s16x8 pf[2];
#pragma unroll
      for (int nt = 0; nt < 2; nt++) {
        pf[nt] =
            *(const s16x8*)&Plds[(wave * 32 + nt * 16 + l16) * 64 + cl];
        lacc[nt] = MFMA32(pf[nt], onesf, lacc[nt]);
      }
#pragma unroll
      for (int dt = 0; dt < 4; dt++) {
        s16x8 vf = *(const s16x8*)&Vt[(dt * 16 + l16) * 64 + cl];
#pragma unroll
        for (int nt = 0; nt < 2; nt++)
          o[nt][dt] = MFMA32(pf[nt], vf, o[nt][dt]);
      }
    }
  }

  if (!split) {
    // normalize + store directly (v2 epilogue): lacc rows quad*4+r match O
#pragma unroll
    for (int nt = 0; nt < 2; nt++) {
      f32x4 inv;
#pragma unroll
      for (int r = 0; r < 4; r++) inv[r] = 1.f / lacc[nt][r];
#pragma unroll
      for (int dt = 0; dt < 4; dt++) {
        float4 v = make_float4(o[nt][dt][0] * inv[0], o[nt][dt][1] * inv[1],
                               o[nt][dt][2] * inv[2], o[nt][dt][3] * inv[3]);
        *(float4*)(out + (size_t)bh * (HD * T_) +
                   (size_t)(dt * 16 + l16) * T_ + q0 + wave * 32 + nt * 16 +
                   quad * 4) = v;
      }
    }
  } else {
    // f32 partials: O_p [slot][d:64][q:128], l_p [slot][q:128]
    const int so = (qt < 8) ? (qt - 4) * 2
                            : (qt < 12) ? 8 + (qt - 8) * 3 : 20 + (qt - 12) * 4;
    const int slot = bh * 36 + so + c;
    float* Op = op + (size_t)slot * 8192;
    float* Lp = lp + (size_t)slot * 128;
#pragma unroll
    for (int nt = 0; nt < 2; nt++) {
      const int qoff = wave * 32 + nt * 16 + quad * 4;
#pragma unroll
      for (int dt = 0; dt < 4; dt++) {
        float4 v = make_float4(o[nt][dt][0], o[nt][dt][1], o[nt][dt][2],
                               o[nt][dt][3]);
        *(float4*)(Op + (dt * 16 + l16) * 128 + qoff) = v;
      }
      if (l16 == 0) {
#pragma unroll
        for (int r = 0; r < 4; r++) Lp[qoff + r] = lacc[nt][r];
      }
    }
  }
}

// combine: out[bh][d][qt*128+q] = sum_c O_c[d][q] / sum_c l_c[q], qt>=4
__global__ __launch_bounds__(256) void combine_kernel(
    const float* __restrict__ op, const float* __restrict__ lp,
    float* __restrict__ out) {
  const int bh = blockIdx.x, qt = blockIdx.y + 4;
  const int nc = (2 * qt + 9) >> 3;  // 2..4 chunks
  const int so = (qt < 8) ? (qt - 4) * 2
                          : (qt < 12) ? 8 + (qt - 8) * 3 : 20 + (qt - 12) * 4;
  const int base = bh * 36 + so;
  const float* Op = op + (size_t)base * 8192;
  const float* Lp = lp + (size_t)base * 128;
  const int t = threadIdx.x;
  const int q = t & 127, dg = t >> 7;
  float lsum = 0.f;
  for (int ci = 0; ci < nc; ci++) lsum += Lp[ci * 128 + q];
  const float inv = 1.f / lsum;
  float* ob = out + (size_t)bh * (HD * T_) + (size_t)qt * 128 + q;
  for (int dd = 0; dd < 32; dd++) {
    const int d = dg * 32 + dd;
    float acc = 0.f;
    for (int ci = 0; ci < nc; ci++) acc += Op[ci * 8192 + d * 128 + q];
    ob[(size_t)d * T_] = acc * inv;
  }
}

extern "C" void kernel_launch(void* const* d_in, const int* in_sizes, int n_in,
                              void* d_out, int out_size, void* d_ws, size_t ws_size,
                              hipStream_t stream) {
  const float* x  = (const float*)d_in[0];
  const float* wq = (const float*)d_in[1];
  const float* wk = (const float*)d_in[2];
  const float* wv = (const float*)d_in[3];
  float* out = (float*)d_out;

  unsigned short* xb  = (unsigned short*)d_ws;       // 4194304 bf16
  unsigned short* wb  = xb + 4194304;                // 3145728 bf16 [Wq;Wk;Wv]
  unsigned short* qkv = wb + 3145728;                // 3 * 4194304 bf16
  float* op = (float*)(qkv + 12582912);              // 1152 * 8192 f32
  float* lp = op + 9437184;                          // 1152 * 128 f32

  cvt_kernel<<<7168, 256, 0, stream>>>(x, wq, wk, wv, xb, wb);
  dim3 g1(24, 64);  // N/128 x M/64 -> 1536 blocks
  qkv_gemm<<<g1, 256, 0, stream>>>(xb, wb, qkv);
  dim3 g2(32, 40);  // bh x LPT chunk-job -> 1280 blocks = 5/CU, <=8 tiles
  attn_kernel<<<g2, 256, 0, stream>>>(qkv, out, op, lp);
  dim3 g3(32, 12);  // bh x (qt-4): sum chunk partials + normalize
  combine_kernel<<<g3, 256, 0, stream>>>(op, lp, out);
}

// Round 9
// 148.158 us; speedup vs baseline: 1.2641x; 1.2641x over previous
//
#include <hip/hip_runtime.h>
#include <hip/hip_bf16.h>
#include <stdint.h>

typedef __attribute__((ext_vector_type(8))) short s16x8;
typedef __attribute__((ext_vector_type(4))) float f32x4;

#define T_   2048
#define NH   16
#define HD   64
#define DIN  1024
#define SCALE_LOG2 0.18033688011112042f  // (1/8)*log2(e)

#define MFMA32(a, b, c) __builtin_amdgcn_mfma_f32_16x16x32_bf16(a, b, c, 0, 0, 0)

// RTNE fp32 -> bf16
__device__ __forceinline__ unsigned short f2bf(float f) {
  union { float f; uint32_t u; } c; c.f = f;
  uint32_t u = c.u;
  return (unsigned short)((u + 0x7FFFu + ((u >> 16) & 1u)) >> 16);
}

__device__ __forceinline__ uint32_t pk_bf16(float a, float b) {
  __hip_bfloat162 h = __float22bfloat162_rn(make_float2(a, b));
  return *reinterpret_cast<uint32_t*>(&h);
}

// async global->LDS, 16B per lane; dest = wave-uniform base + lane*16
#define GLL(gp, lp) __builtin_amdgcn_global_load_lds( \
    (__attribute__((address_space(1))) void*)(gp),    \
    (__attribute__((address_space(3))) void*)(lp), 16, 0, 0)

// ---------------- kernel 1: fp32 -> bf16 conversion ----------------
__global__ __launch_bounds__(256) void cvt_kernel(
    const float* __restrict__ x,  const float* __restrict__ wq,
    const float* __restrict__ wk, const float* __restrict__ wv,
    unsigned short* __restrict__ xb, unsigned short* __restrict__ wb) {
  int i = (blockIdx.x * 256 + threadIdx.x) * 4;
  float4 v;
  unsigned short* dp;
  if (i < 4194304) {
    v = *(const float4*)(x + i);
    dp = xb + i;
  } else {
    int j = i - 4194304;
    int seg = j >> 20, r = j & 1048575;
    const float* w = (seg == 0) ? wq : (seg == 1) ? wk : wv;
    v = *(const float4*)(w + r);
    dp = wb + j;
  }
  ushort4 o;
  o.x = f2bf(v.x); o.y = f2bf(v.y); o.z = f2bf(v.z); o.w = f2bf(v.w);
  *(ushort4*)dp = o;
}

// ---------------- kernel 2: QKV projection GEMM (BK=128, r7-proven) -------
// BK64 measured 46.5us (r6: MfmaUtil 22.6, nothing saturated, 16 latency-
// exposed iters). BK=128: 8 iters, 32 MFMA/wave/iter; r7 HW-passed and its
// profile showed no kernel above 42.2us -> BK128 gemm <= 42. LDS 48KB
// (A 64x128 + B 128x128) -> 3 blocks/CU. 16-way XOR swizzle pre-applied on
// the global source (GLL dest linear); readers use ((ks*4+quad)^l16)*8.
// Epilogue: Q pre-scaled by SCALE_LOG2; V transposed [bh][d][t].
__global__ __launch_bounds__(256) void qkv_gemm(
    const unsigned short* __restrict__ A, const unsigned short* __restrict__ Bm,
    unsigned short* __restrict__ qkv) {
  __shared__ __attribute__((aligned(16))) unsigned short Alds[64 * 128];
  __shared__ __attribute__((aligned(16))) unsigned short Blds[128 * 128];
  const int tid = threadIdx.x;
  const int lane = tid & 63, wave = tid >> 6;
  const int wm = wave >> 1, wn = wave & 1;  // 2x2 waves over 64x128
  const int m0 = blockIdx.y * 64, n0 = blockIdx.x * 128;

  f32x4 acc[2][4] = {};

  // staging: per GLL issue a wave covers 4 rows (16 lanes/row of 128 elems).
  // row = wave*4 + (lane>>4) (+16/issue), phys chunk = lane&15; source col
  // chunk pre-swizzled ^ (row&15) (issue-invariant since +16 preserves &15).
  const int srow = wave * 4 + (lane >> 4);
  const int schunk = (lane & 15) ^ (srow & 15);
  const unsigned short* ag = A  + (size_t)(m0 + srow) * DIN + schunk * 8;
  const unsigned short* bg = Bm + (size_t)(n0 + srow) * DIN + schunk * 8;
  unsigned short* al = &Alds[wave * 4 * 128];
  unsigned short* bl = &Blds[wave * 4 * 128];

  const int l16 = lane & 15, quad = lane >> 4;

  for (int k0 = 0; k0 < DIN; k0 += 128) {
    __syncthreads();
#pragma unroll
    for (int i = 0; i < 4; i++)
      GLL(ag + (size_t)(i * 16) * DIN + k0, al + i * 16 * 128);
#pragma unroll
    for (int i = 0; i < 8; i++)
      GLL(bg + (size_t)(i * 16) * DIN + k0, bl + i * 16 * 128);
    __syncthreads();
#pragma unroll
    for (int ks = 0; ks < 4; ks++) {
      const int cl = ((ks * 4 + quad) ^ l16) * 8;
      s16x8 af[2], bf[4];
#pragma unroll
      for (int mt = 0; mt < 2; mt++)
        af[mt] = *(const s16x8*)&Alds[(wm * 32 + mt * 16 + l16) * 128 + cl];
#pragma unroll
      for (int nt = 0; nt < 4; nt++)
        bf[nt] = *(const s16x8*)&Blds[(wn * 64 + nt * 16 + l16) * 128 + cl];
#pragma unroll
      for (int mt = 0; mt < 2; mt++)
#pragma unroll
        for (int nt = 0; nt < 4; nt++)
          acc[mt][nt] = MFMA32(af[mt], bf[nt], acc[mt][nt]);
    }
  }

#pragma unroll
  for (int mt = 0; mt < 2; mt++) {
    int mbase = m0 + wm * 32 + mt * 16 + (quad << 2);
    int b = mbase >> 11, t = mbase & 2047;
#pragma unroll
    for (int nt = 0; nt < 4; nt++) {
      int n = n0 + wn * 64 + nt * 16 + l16;
      int sel = n >> 10, h = (n >> 6) & 15, d = n & 63;
      int bh = b * NH + h;
      if (sel == 2) {
        ushort4 pk;
        pk.x = f2bf(acc[mt][nt][0]); pk.y = f2bf(acc[mt][nt][1]);
        pk.z = f2bf(acc[mt][nt][2]); pk.w = f2bf(acc[mt][nt][3]);
        *(ushort4*)&qkv[8388608 + (size_t)(bh * HD + d) * T_ + t] = pk;
      } else {
        float qs = (sel == 0) ? SCALE_LOG2 : 1.f;  // fold softmax scale into Q
#pragma unroll
        for (int r = 0; r < 4; r++)
          qkv[(size_t)sel * 4194304 + (size_t)(bh * T_ + t + r) * HD + d] =
              f2bf(acc[mt][nt][r] * qs);
      }
    }
  }
}

// ---------------- kernel 3: causal flash attention (r0-exact body) --------
// r0's kernel is the best-measured attn path (43.5us, no combine). Only
// change: the y->qt mapping. r0's qt-descending was a no-op (all 1024
// blocks co-resident). New mapping: period-256 complementary groups so a
// round-robin-ish dispatcher gives every CU exactly 66 k-tiles:
//   g = y>>3, r = y&7; qt = {31-r, r, 23-r, 8+r}[g]
//   lengths (32-r)+(r+1)+(24-r)+(9+r) = 66 for all r.
// If dispatch is random this is no worse than r0. Inner body untouched.
__global__ __launch_bounds__(256) void attn_kernel(
    const unsigned short* __restrict__ qkv, float* __restrict__ out) {
  __shared__ __attribute__((aligned(16))) unsigned short Klds[64 * 64];
  __shared__ __attribute__((aligned(16))) unsigned short Vt[64 * 64];
  __shared__ __attribute__((aligned(16))) unsigned short Plds[64 * 64];

  const int lane = threadIdx.x & 63, wave = threadIdx.x >> 6;
  const int l16 = lane & 15, quad = lane >> 4;
  const int swl = l16 & 7;
  const int y = blockIdx.y, g = y >> 3, r = y & 7;
  const int qt = (g == 0) ? 31 - r : (g == 1) ? r : (g == 2) ? 23 - r : 8 + r;
  const int bh = blockIdx.x;
  const int q0 = qt * 64;
  const size_t bh_off = (size_t)bh * (T_ * HD);
  const unsigned short* Q  = qkv + bh_off;            // [t][d], pre-scaled
  const unsigned short* Kb = qkv + 4194304 + bh_off;  // [t][d]
  const unsigned short* Vb = qkv + 8388608 + bh_off;  // [d][t]

  s16x8 qf[2];
  {
    const unsigned short* qp =
        Q + (size_t)(q0 + wave * 16 + l16) * HD + quad * 8;
    qf[0] = *(const s16x8*)(qp);
    qf[1] = *(const s16x8*)(qp + 32);
  }

  const int sr = threadIdx.x >> 3;                 // staging row 0..31
  const int sc = (threadIdx.x & 7) * 8;            // linear global chunk
  const int swc = (((threadIdx.x & 7) ^ (sr & 7))) * 8;  // swizzled LDS chunk

  s16x8 kr0 = *(const s16x8*)&Kb[(size_t)sr * HD + sc];
  s16x8 kr1 = *(const s16x8*)&Kb[(size_t)(sr + 32) * HD + sc];
  s16x8 vr0 = *(const s16x8*)&Vb[(size_t)sr * T_ + sc];
  s16x8 vr1 = *(const s16x8*)&Vb[(size_t)(sr + 32) * T_ + sc];

  const s16x8 onesf = {0x3F80, 0x3F80, 0x3F80, 0x3F80,
                       0x3F80, 0x3F80, 0x3F80, 0x3F80};  // bf16 1.0 x8
  f32x4 o[4] = {};
  f32x4 lacc = {};

  uint32_t* prow = (uint32_t*)&Plds[(wave * 16 + l16) * 64];
  const unsigned short* prd = &Plds[(wave * 16 + l16) * 64];

  for (int kt = 0; kt <= qt; kt++) {
    __syncthreads();
    *(s16x8*)&Klds[sr * 64 + swc] = kr0;
    *(s16x8*)&Klds[(sr + 32) * 64 + swc] = kr1;
    *(s16x8*)&Vt[sr * 64 + swc] = vr0;
    *(s16x8*)&Vt[(sr + 32) * 64 + swc] = vr1;
    if (kt < qt) {
      const unsigned short* kp = Kb + (size_t)(kt + 1) * 64 * HD;
      const unsigned short* vp = Vb + (kt + 1) * 64;
      kr0 = *(const s16x8*)&kp[(size_t)sr * HD + sc];
      kr1 = *(const s16x8*)&kp[(size_t)(sr + 32) * HD + sc];
      vr0 = *(const s16x8*)&vp[(size_t)sr * T_ + sc];
      vr1 = *(const s16x8*)&vp[(size_t)(sr + 32) * T_ + sc];
    }
    __syncthreads();

    // S^T = K @ Q^T : m=key, n=q
    f32x4 s[4] = {};
#pragma unroll
    for (int kk = 0; kk < 2; kk++) {
      const int cl = ((kk * 4 + quad) ^ swl) * 8;
#pragma unroll
      for (int nt = 0; nt < 4; nt++) {
        s16x8 kf = *(const s16x8*)&Klds[(nt * 16 + l16) * 64 + cl];
        s[nt] = MFMA32(kf, qf[kk], s[nt]);
      }
    }

    // P write: logical chunk 2nt+(quad>>1), phys = ^(l16&7), inner (quad&1)*2
    if (kt < qt) {  // fully visible tile: no mask code
#pragma unroll
      for (int nt = 0; nt < 4; nt++) {
        float p0 = exp2f(s[nt][0]);
        float p1 = exp2f(s[nt][1]);
        float p2 = exp2f(s[nt][2]);
        float p3 = exp2f(s[nt][3]);
        *(uint2*)&prow[(((2 * nt + (quad >> 1)) ^ swl) << 2) + (quad & 1) * 2] =
            make_uint2(pk_bf16(p0, p1), pk_bf16(p2, p3));
      }
    } else {  // diagonal tile: causal mask
      const int lim = wave * 16 + l16;
#pragma unroll
      for (int nt = 0; nt < 4; nt++) {
        const int kb = nt * 16 + quad * 4;
        float p0 = (kb + 0 <= lim) ? exp2f(s[nt][0]) : 0.f;
        float p1 = (kb + 1 <= lim) ? exp2f(s[nt][1]) : 0.f;
        float p2 = (kb + 2 <= lim) ? exp2f(s[nt][2]) : 0.f;
        float p3 = (kb + 3 <= lim) ? exp2f(s[nt][3]) : 0.f;
        *(uint2*)&prow[(((2 * nt + (quad >> 1)) ^ swl) << 2) + (quad & 1) * 2] =
            make_uint2(pk_bf16(p0, p1), pk_bf16(p2, p3));
      }
    }

    // O += P @ V ; l += P @ 1
#pragma unroll
    for (int kk = 0; kk < 2; kk++) {
      const int cl = ((kk * 4 + quad) ^ swl) * 8;
      s16x8 pf = *(const s16x8*)&prd[cl];
      lacc = MFMA32(pf, onesf, lacc);
#pragma unroll
      for (int dt = 0; dt < 4; dt++) {
        s16x8 vf = *(const s16x8*)&Vt[(dt * 16 + l16) * 64 + cl];
        o[dt] = MFMA32(pf, vf, o[dt]);
      }
    }
  }

  // normalize + store: lacc row=quad*4+r matches O rows exactly
  f32x4 inv;
#pragma unroll
  for (int r2 = 0; r2 < 4; r2++) inv[r2] = 1.f / lacc[r2];
#pragma unroll
  for (int dt = 0; dt < 4; dt++) {
    float4 v = make_float4(o[dt][0] * inv[0], o[dt][1] * inv[1],
                           o[dt][2] * inv[2], o[dt][3] * inv[3]);
    *(float4*)(out + (size_t)bh * (HD * T_) + (size_t)(dt * 16 + l16) * T_ +
               q0 + wave * 16 + quad * 4) = v;
  }
}

extern "C" void kernel_launch(void* const* d_in, const int* in_sizes, int n_in,
                              void* d_out, int out_size, void* d_ws, size_t ws_size,
                              hipStream_t stream) {
  const float* x  = (const float*)d_in[0];
  const float* wq = (const float*)d_in[1];
  const float* wk = (const float*)d_in[2];
  const float* wv = (const float*)d_in[3];
  float* out = (float*)d_out;

  unsigned short* xb  = (unsigned short*)d_ws;       // 4194304 bf16
  unsigned short* wb  = xb + 4194304;                // 3145728 bf16 [Wq;Wk;Wv]
  unsigned short* qkv = wb + 3145728;                // 3 * 4194304 bf16

  cvt_kernel<<<7168, 256, 0, stream>>>(x, wq, wk, wv, xb, wb);
  dim3 g1(24, 64);  // N/128 x M/64 -> 1536 blocks, BK=128 -> 8 iters
  qkv_gemm<<<g1, 256, 0, stream>>>(xb, wb, qkv);
  dim3 g2(32, 32);  // bh x y (complementary-group qt permutation)
  attn_kernel<<<g2, 256, 0, stream>>>(qkv, out);
}